// Round 6
// baseline (112.779 us; speedup 1.0000x reference)
//
#include <hip/hip_runtime.h>

typedef unsigned int uint32;
typedef unsigned short ushort;

typedef __bf16  bf16x8   __attribute__((ext_vector_type(8)));
typedef float   f32x4    __attribute__((ext_vector_type(4)));
typedef ushort  ushort4v __attribute__((ext_vector_type(4)));

#define K_CODES 1024
#define CDIM    64
#define HWALL   4096      // H*W
#define CHW     262144    // CDIM*HWALL
#define TROWS   64        // z-rows per tile (2 tiles per block)

__device__ __forceinline__ ushort f2bf(float f) {
    uint32 u = __builtin_bit_cast(uint32, f);
    u += 0x7FFFu + ((u >> 16) & 1u);   // RNE
    return (ushort)(u >> 16);
}

// Pass 0 (tiny, coalesced): codebook fp32 -> bf16 row-major + negbias[k] =
// -0.5*||e_k||^2. Also zeroes the loss cell out[0].
__global__ __launch_bounds__(256) void prep_kernel(const float* __restrict__ cb,
                                                   ushort* __restrict__ cbb,
                                                   float* __restrict__ negbias,
                                                   float* __restrict__ out) {
    int t = threadIdx.x;
    if (blockIdx.x == 0 && t == 0) out[0] = 0.f;
    int k = blockIdx.x * 4 + (t >> 6);
    int c = t & 63;
    float v = cb[k * 64 + c];
    cbb[k * 64 + c] = f2bf(v);
    float s = v * v;
    #pragma unroll
    for (int d = 1; d < 64; d <<= 1) s += __shfl_xor(s, d, 64);
    if (c == 0) negbias[k] = -0.5f * s;
}

// R16: OCCUPANCY. R5 re-anchor proved the baseline schedule is correct and
// the swap family was a real regression. Baseline vq ~42us moves only ~34MB
// useful (6us at BW roofline) with every pipe idle (MfmaUtil 4.6, VALUBusy
// 8.5, Occupancy 38%): latency-bound at 1 block/CU (16/32 waves), all waves
// lock-stepped through 6 barriers + HBM/gather latency chains.
// Change (single variable, geometry only): same schedule at 512 blocks x
// 512 threads (8 waves, two 64-row tiles) -> 2 independent blocks/CU,
// 32 waves/CU; one block's GEMM hides the other's barriers/latency.
// Each wave covers 128 codes in two groups of 4 n-tiles (B-slice reloaded
// from L2-hot cbb between groups) to keep VGPR < 128 for 2-block residency.
__global__ __launch_bounds__(512, 4) void vq_kernel(const float* __restrict__ z,
                                                    const ushort* __restrict__ cbb,
                                                    const float* __restrict__ negbias,
                                                    float* __restrict__ out) {
    __shared__ __align__(16) ushort Abf[TROWS * 72];  // 9 KB A-tile, pitch 72
    __shared__ float partial[8][TROWS];               // 2 KB packed argmax keys
    __shared__ float loss_acc;

    const int t   = threadIdx.x;
    const int blk = blockIdx.x;
    const int b   = blk >> 5;                 // 32 blocks per batch image
    const int hw0 = (blk & 31) << 7;          // 128 rows per block
    const int zoff0 = b * CHW + hw0;

    if (t == 0) loss_acc = 0.f;

    const int r  = t & 63;     // z-row within tile (lanes consecutive -> coalesced)
    const int cg = t >> 6;     // c-group 0..7 (== wave id)
    const int w  = t >> 6;     // wave 0..7: owns codes [w*128, +128)
    const int l  = t & 63;
    const int m  = l & 15;     // B col within n-tile / key-embedded code low bits
    const int q  = l >> 4;     // k-quad

    // ---- issue tile-0 z loads (deepest dep) ----
    float z0v[8];
    #pragma unroll
    for (int j = 0; j < 8; ++j) z0v[j] = z[zoff0 + (cg * 8 + j) * HWALL + r];

    // ---- codebook slice regs: 4 n-tiles at a time (group g of 2) ----
    bf16x8 Bv[4][2];
    float  nb[4];
    auto loadB = [&](int g) {
        #pragma unroll
        for (int j = 0; j < 4; ++j) {
            int code = (((w << 3) + (g << 2) + j) << 4) + m;
            Bv[j][0] = *(const bf16x8*)&cbb[(code << 6) + (q << 3)];
            Bv[j][1] = *(const bf16x8*)&cbb[(code << 6) + 32 + (q << 3)];
            nb[j] = negbias[code];
        }
    };
    loadB(0);   // tile-0 group-A hides under z-load latency

    // ---- issue tile-1 z loads; they arrive during tile-0 GEMM ----
    float z1v[8];
    #pragma unroll
    for (int j = 0; j < 8; ++j) z1v[j] = z[zoff0 + 64 + (cg * 8 + j) * HWALL + r];

    // ---- stage tile-0 -> Abf (bf16, pitch 72) ----
    {
        ushort4v pk0, pk1;
        #pragma unroll
        for (int j = 0; j < 4; ++j) { pk0[j] = f2bf(z0v[j]); pk1[j] = f2bf(z0v[4 + j]); }
        *(ushort4v*)&Abf[r * 72 + cg * 8]     = pk0;
        *(ushort4v*)&Abf[r * 72 + cg * 8 + 4] = pk1;
    }
    __syncthreads();

    float lsum = 0.f;

    // GEMM over current Abf: 4 m-blocks x 8 n-tiles (2 reg-B groups),
    // packed-key argmax -> partial[w][0..63].
    auto do_gemm = [&](bool haveA) {
        float best[16];
        #pragma unroll
        for (int i = 0; i < 16; ++i) best[i] = -__builtin_inff();
        #pragma unroll
        for (int g = 0; g < 2; ++g) {
            if (!(g == 0 && haveA)) loadB(g);
            #pragma unroll
            for (int mbb = 0; mbb < 4; ++mbb) {
                bf16x8 a0 = *(const bf16x8*)&Abf[(mbb * 16 + m) * 72 + (q << 3)];
                bf16x8 a1 = *(const bf16x8*)&Abf[(mbb * 16 + m) * 72 + 32 + (q << 3)];
                #pragma unroll
                for (int j = 0; j < 4; ++j) {
                    uint32 tag = 1023u - (uint32)(((((w << 3) + (g << 2) + j) << 4)) + m);
                    f32x4 acc0;
                    acc0[0] = nb[j]; acc0[1] = nb[j]; acc0[2] = nb[j]; acc0[3] = nb[j];
                    f32x4 acc = __builtin_amdgcn_mfma_f32_16x16x32_bf16(a0, Bv[j][0], acc0, 0, 0, 0);
                    acc       = __builtin_amdgcn_mfma_f32_16x16x32_bf16(a1, Bv[j][1], acc,  0, 0, 0);
                    #pragma unroll
                    for (int rr = 0; rr < 4; ++rr) {
                        uint32 kb = (__builtin_bit_cast(uint32, acc[rr]) & 0xFFFFFC00u) | tag;
                        int bi = mbb * 4 + rr;
                        best[bi] = fmaxf(best[bi], __builtin_bit_cast(float, kb));
                    }
                }
            }
        }
        // single checkpoint: reduce over the 16 m-lanes, store 4 m-blocks
        #pragma unroll
        for (int i = 0; i < 16; ++i) {
            float v = best[i];
            #pragma unroll
            for (int d = 1; d < 16; d <<= 1) v = fmaxf(v, __shfl_xor(v, d, 64));
            best[i] = v;
        }
        if (m == 0) {
            #pragma unroll
            for (int mb2 = 0; mb2 < 4; ++mb2)
                #pragma unroll
                for (int rr = 0; rr < 4; ++rr)
                    partial[w][mb2 * 16 + (q << 2) + rr] = best[mb2 * 4 + rr];
        }
    };

    // ================= tile 0 =================
    do_gemm(true);
    __syncthreads();

    // combine + issue gather (bf16 codebook, 2x8B); latency hides under restage
    ushort4v ec0, ec1;
    {
        float km = partial[0][r];
        #pragma unroll
        for (int j = 1; j < 8; ++j) km = fmaxf(km, partial[j][r]);
        int idx0 = 1023 - (int)(__builtin_bit_cast(uint32, km) & 1023u);
        ec0 = *(const ushort4v*)&cbb[(idx0 << 6) + (cg << 3)];
        ec1 = *(const ushort4v*)&cbb[(idx0 << 6) + (cg << 3) + 4];
    }

    // restage tile-1 (tile-0 zp lives in z0v regs, Abf free to overwrite)
    {
        ushort4v pk0, pk1;
        #pragma unroll
        for (int j = 0; j < 4; ++j) { pk0[j] = f2bf(z1v[j]); pk1[j] = f2bf(z1v[4 + j]); }
        *(ushort4v*)&Abf[r * 72 + cg * 8]     = pk0;
        *(ushort4v*)&Abf[r * 72 + cg * 8 + 4] = pk1;
    }
    __syncthreads();

    // consume tile-0: stores retire async while gemm1 runs on the MFMA pipe
    #pragma unroll
    for (int j = 0; j < 4; ++j) {
        float v0 = __builtin_bit_cast(float, (uint32)ec0[j] << 16);
        float v1 = __builtin_bit_cast(float, (uint32)ec1[j] << 16);
        out[1 + zoff0 + (cg * 8 + j) * HWALL + r]     = v0;   // ST fwd == vq
        out[1 + zoff0 + (cg * 8 + 4 + j) * HWALL + r] = v1;
        float d0 = v0 - z0v[j], d1 = v1 - z0v[4 + j];
        lsum += d0 * d0 + d1 * d1;
    }

    // ================= tile 1 =================
    do_gemm(false);
    __syncthreads();

    {
        float km = partial[0][r];
        #pragma unroll
        for (int j = 1; j < 8; ++j) km = fmaxf(km, partial[j][r]);
        int idx1 = 1023 - (int)(__builtin_bit_cast(uint32, km) & 1023u);
        ushort4v f0 = *(const ushort4v*)&cbb[(idx1 << 6) + (cg << 3)];
        ushort4v f1 = *(const ushort4v*)&cbb[(idx1 << 6) + (cg << 3) + 4];
        #pragma unroll
        for (int j = 0; j < 4; ++j) {
            float v0 = __builtin_bit_cast(float, (uint32)f0[j] << 16);
            float v1 = __builtin_bit_cast(float, (uint32)f1[j] << 16);
            out[1 + zoff0 + 64 + (cg * 8 + j) * HWALL + r]     = v0;
            out[1 + zoff0 + 64 + (cg * 8 + 4 + j) * HWALL + r] = v1;
            float d0 = v0 - z1v[j], d1 = v1 - z1v[4 + j];
            lsum += d0 * d0 + d1 * d1;
        }
    }

    // ---- loss: wave reduce -> LDS -> one global atomic per block ----
    #pragma unroll
    for (int d = 1; d < 64; d <<= 1) lsum += __shfl_xor(lsum, d, 64);
    if (l == 0) atomicAdd(&loss_acc, lsum);
    __syncthreads();
    if (t == 0) atomicAdd(out, loss_acc * (1.25f / 4194304.f));  // (1+BETA)/numel
}

extern "C" void kernel_launch(void* const* d_in, const int* in_sizes, int n_in,
                              void* d_out, int out_size, void* d_ws, size_t ws_size,
                              hipStream_t stream) {
    (void)in_sizes; (void)n_in; (void)out_size; (void)ws_size;
    const float* z  = (const float*)d_in[0];
    const float* cb = (const float*)d_in[1];
    float* out = (float*)d_out;
    ushort* cbb = (ushort*)d_ws;
    float* negbias = (float*)((char*)d_ws + K_CODES * CDIM * sizeof(ushort));

    prep_kernel<<<dim3(256), dim3(256), 0, stream>>>(cb, cbb, negbias, out);
    vq_kernel<<<dim3(512), dim3(512), 0, stream>>>(z, cbb, negbias, out);
}